// Round 16
// baseline (34.273 us; speedup 1.0000x reference)
//
#include <hip/hip_runtime.h>

#define N_DIM 2048
#define F_DIM 64

typedef __attribute__((ext_vector_type(4))) float  f32x4;
typedef __attribute__((ext_vector_type(8))) short  s16x8;
typedef __attribute__((ext_vector_type(8))) __bf16 bf16x8;

typedef const __attribute__((address_space(1))) void gas_t;
typedef __attribute__((address_space(3))) void las_t;

static __device__ __forceinline__ unsigned short f2bf(float f) {
  unsigned int u = __builtin_bit_cast(unsigned int, f);
  u += 0x7fffu + ((u >> 16) & 1u);      // RNE to bf16
  return (unsigned short)(u >> 16);
}

// Prep (grid 72):
//  blocks 0..63  — MFMA B-fragments of bf16(v): lane l holds
//    B[k = 8*(l/16)+j][col = l%16], stored [kt(64)][tile(4)][lane(64)][j(8)]
//  blocks 64..71 — s_half[k] = 0.5 * sum_f v[k][f]^2
__global__ __launch_bounds__(256) void fm_prep(const float* __restrict__ v,
                                               unsigned short* __restrict__ vb,
                                               float* __restrict__ sh) {
  const int blk = blockIdx.x;
  const int tid = threadIdx.x;
  if (blk < 64) {
    const int g  = blk * 256 + tid;
    const int fl = g & 63;
    const int t  = (g >> 6) & 3;
    const int kt = g >> 8;
    const int kbase = kt * 32 + ((fl >> 4) << 3);
    const int f = t * 16 + (fl & 15);
    s16x8 a;
#pragma unroll
    for (int j = 0; j < 8; ++j)
      a[j] = (short)f2bf(v[(size_t)(kbase + j) * F_DIM + f]);
    *(s16x8*)(vb + (size_t)g * 8) = a;
  } else {
    const int k = (blk - 64) * 256 + tid;
    const f32x4* row = (const f32x4*)(v + (size_t)k * F_DIM);
    float s = 0.0f;
#pragma unroll
    for (int i = 0; i < 16; ++i) {
      f32x4 q = row[i];
      s += q[0]*q[0] + q[1]*q[1] + q[2]*q[2] + q[3]*q[3];
    }
    sh[k] = 0.5f * s;
  }
}

// Main: 512 blocks x 256 threads (4 waves), R7 wave/tile decomposition.
// x staged via NON-TEMPORAL global_load_lds (aux=2: CPol NT bit — bypass
// L2/L3 allocation; theory: cache-fill path caps cached streams at ~5 TB/s
// while nt delivers ~6.9 TB/s, R9) into WAVE-PRIVATE double-buffered 4 KiB
// slabs. Each 128-B line covered by EXACTLY ONE instruction (8 lanes x 16 B,
// XOR-permuted chunks) -> nt-safe, no double-fetch. No mid-loop barriers:
// counted s_waitcnt vmcnt(N) + sched_barrier fences (N=12 steady, 8@s0,
// 4@s15; FIFO order vb(s+1) -> wait slab s -> compute -> gload s+2).
// vb register-prefetch depth 1 (cached, L2-resident). lin = x.w1 - 0.5*x^2.s
// in fp32 (w1/sh from LDS). Epilogue overlays accW/linL on the slab region.
__global__ __launch_bounds__(256, 2) void fm_main(const float* __restrict__ x,
                                                  const float* __restrict__ w0,
                                                  const float* __restrict__ w1,
                                                  const unsigned short* __restrict__ vb,
                                                  const float* __restrict__ sh,
                                                  float* __restrict__ out) {
  extern __shared__ __align__(16) char smem[];
  // layout: [0,32K) wave slabs (w*8K + buf*4K); [32K,40K) w1L; [40K,48K) shL
  // epilogue overlay: [0,24K) accW, [24K,24.5K) linL
  const int tid  = threadIdx.x;
  const int lane = tid & 63;
  const int w    = tid >> 6;            // 0..3
  const int rowbase = blockIdx.x * 32;
  const int g8   = ((lane >> 4) << 3);  // fragment k-subchunk: 0,8,16,24

  float* w1L = (float*)(smem + 32768);
  float* shL = (float*)(smem + 40960);
  char*  slab0 = smem + (w << 13);      // this wave's buf 0
  char*  slab1 = slab0 + 4096;          // buf 1

  const int kw = w * 512;               // this wave's K range (16 slabs of 32)

  // staging src: lane l covers row (l>>3) of 8-row group, chunk (l&7)^(l>>3)
  // -> LDS linear [row][chunk'] holds x[row][chunk' ^ (row&7)]
  const float* xgl = x + (size_t)(rowbase + (lane >> 3)) * N_DIM + kw
                   + (((lane & 7) ^ (lane >> 3)) << 2);
  const unsigned short* vbase = vb + ((size_t)w * 4096 + lane) * 8;

  // fragment ds offsets: tile h row = 16h+(l&15); chunk c ^ (row&7), row&7=l&7
  const int r7  = lane & 7;
  const int c0  = (lane >> 4) << 1;
  const int offA0 = (lane & 15) * 128 + (((c0)     ^ r7) << 4);
  const int offB0 = (lane & 15) * 128 + (((c0 + 1) ^ r7) << 4);
  const int offA1 = offA0 + 2048;       // rows 16-31
  const int offB1 = offB0 + 2048;

  // ---- stage w1/sh into LDS; barrier drains these 4 loads only ----
  {
    const int t8 = tid << 3;
    *(f32x4*)&w1L[t8]     = *(const f32x4*)(w1 + t8);
    *(f32x4*)&w1L[t8 + 4] = *(const f32x4*)(w1 + t8 + 4);
    *(f32x4*)&shL[t8]     = *(const f32x4*)(sh + t8);
    *(f32x4*)&shL[t8 + 4] = *(const f32x4*)(sh + t8 + 4);
  }
  __syncthreads();

  // ---- prologue (FIFO order matters): vb(0), gload slab0, gload slab1 ----
  s16x8 pb[2][4];
#pragma unroll
  for (int t = 0; t < 4; ++t)
    pb[0][t] = *(const s16x8*)(vbase + t * 512);
#pragma unroll
  for (int i = 0; i < 4; ++i)
    __builtin_amdgcn_global_load_lds((gas_t*)(xgl + (size_t)i * 8 * N_DIM),
                                     (las_t*)(slab0 + i * 1024), 16, 0, 2);
#pragma unroll
  for (int i = 0; i < 4; ++i)
    __builtin_amdgcn_global_load_lds((gas_t*)(xgl + (size_t)i * 8 * N_DIM + 32),
                                     (las_t*)(slab1 + i * 1024), 16, 0, 2);

  f32x4 acc[2][4] = {};
  float linA = 0.0f, linB = 0.0f;

#pragma unroll
  for (int s = 0; s < 16; ++s) {
    // 1. vb prefetch FIRST (depth 1, L2-resident)
    if (s < 15) {
      const unsigned short* vbp = vbase + (size_t)(s + 1) * 2048;
#pragma unroll
      for (int t = 0; t < 4; ++t)
        pb[(s + 1) & 1][t] = *(const s16x8*)(vbp + t * 512);
    }
    // 2. wait for slab s (counted; never drains the pipeline)
    __builtin_amdgcn_sched_barrier(0);
    if (s == 0)       asm volatile("s_waitcnt vmcnt(8)"  ::: "memory");
    else if (s == 15) asm volatile("s_waitcnt vmcnt(4)"  ::: "memory");
    else              asm volatile("s_waitcnt vmcnt(12)" ::: "memory");
    __builtin_amdgcn_sched_barrier(0);
    // 3. fragment reads from slab s
    const char* xq = (s & 1) ? slab1 : slab0;
    f32x4 xa = *(const f32x4*)(xq + offA0);
    f32x4 xb = *(const f32x4*)(xq + offB0);
    f32x4 xc = *(const f32x4*)(xq + offA1);
    f32x4 xd = *(const f32x4*)(xq + offB1);
    const int ki = kw + s * 32 + g8;
    f32x4 wa  = *(const f32x4*)(&w1L[ki]);
    f32x4 wb2 = *(const f32x4*)(&w1L[ki + 4]);
    f32x4 sa  = *(const f32x4*)(&shL[ki]);
    f32x4 sb2 = *(const f32x4*)(&shL[ki + 4]);
    // 4. compute
#pragma unroll
    for (int i = 0; i < 4; ++i) {
      linA = fmaf(xa[i], wa[i]  - xa[i] * sa[i],  linA);
      linA = fmaf(xb[i], wb2[i] - xb[i] * sb2[i], linA);
      linB = fmaf(xc[i], wa[i]  - xc[i] * sa[i],  linB);
      linB = fmaf(xd[i], wb2[i] - xd[i] * sb2[i], linB);
    }
    bf16x8 Alo, Ahi;
#pragma unroll
    for (int i = 0; i < 4; ++i) {
      Alo[i]     = (__bf16)xa[i];
      Alo[4 + i] = (__bf16)xb[i];
      Ahi[i]     = (__bf16)xc[i];
      Ahi[4 + i] = (__bf16)xd[i];
    }
#pragma unroll
    for (int t = 0; t < 4; ++t) {
      bf16x8 Bv = __builtin_bit_cast(bf16x8, pb[s & 1][t]);
      acc[0][t] = __builtin_amdgcn_mfma_f32_16x16x32_bf16(Alo, Bv, acc[0][t], 0, 0, 0);
      acc[1][t] = __builtin_amdgcn_mfma_f32_16x16x32_bf16(Ahi, Bv, acc[1][t], 0, 0, 0);
    }
    // 5. refill this buffer with slab s+2 (reads above already sampled LDS;
    //    the async write lands >=400cyc after issue, far later)
    __builtin_amdgcn_sched_barrier(0);
    if (s < 14) {
      char* dst = (s & 1) ? slab1 : slab0;
#pragma unroll
      for (int i = 0; i < 4; ++i)
        __builtin_amdgcn_global_load_lds(
            (gas_t*)(xgl + (size_t)i * 8 * N_DIM + (s + 2) * 32),
            (las_t*)(dst + i * 1024), 16, 0, 2);
    }
  }

  // ---- lin reduce: lanes {r,r+16,r+32,r+48} hold partials of row r ----
  linA += __shfl_xor(linA, 16);
  linA += __shfl_xor(linA, 32);
  linB += __shfl_xor(linB, 16);
  linB += __shfl_xor(linB, 32);

  // ---- epilogue overlays the slab region: all waves must be done ----
  __syncthreads();
  f32x4 (*accW)[8][64] = (f32x4(*)[8][64])smem;           // [3][8][64]
  float (*linL)[2][16] = (float(*)[2][16])(smem + 24576); // [4][2][16]

  if (lane < 16) {
    linL[w][0][lane] = linA;
    linL[w][1][lane] = linB;
  }
  if (w > 0) {
#pragma unroll
    for (int h = 0; h < 2; ++h)
#pragma unroll
      for (int t = 0; t < 4; ++t)
        accW[w - 1][h * 4 + t][lane] = acc[h][t];
  }
  __syncthreads();

  if (w == 0) {
#pragma unroll
    for (int ww = 0; ww < 3; ++ww)
#pragma unroll
      for (int h = 0; h < 2; ++h)
#pragma unroll
        for (int t = 0; t < 4; ++t)
          acc[h][t] += accW[ww][h * 4 + t][lane];

    // C layout: col = lane&15 (within F-tile t), row = 4*(lane>>4) + r
    float p[2][4];
#pragma unroll
    for (int h = 0; h < 2; ++h)
#pragma unroll
      for (int r = 0; r < 4; ++r) {
        float q = 0.0f;
#pragma unroll
        for (int t = 0; t < 4; ++t)
          q += acc[h][t][r] * acc[h][t][r];
        q += __shfl_xor(q, 1);
        q += __shfl_xor(q, 2);
        q += __shfl_xor(q, 4);
        q += __shfl_xor(q, 8);
        p[h][r] = q;
      }
    if ((lane & 15) == 0) {
      const int g = lane >> 4;
      const float w0v = w0[0];
#pragma unroll
      for (int h = 0; h < 2; ++h)
#pragma unroll
        for (int r = 0; r < 4; ++r) {
          const int row = g * 4 + r;
          float lt = linL[0][h][row] + linL[1][h][row]
                   + linL[2][h][row] + linL[3][h][row];
          out[rowbase + h * 16 + row] = w0v + lt + 0.5f * p[h][r];
        }
    }
  }
}

extern "C" void kernel_launch(void* const* d_in, const int* in_sizes, int n_in,
                              void* d_out, int out_size, void* d_ws, size_t ws_size,
                              hipStream_t stream) {
  const float* x  = (const float*)d_in[0];
  const float* w0 = (const float*)d_in[1];
  const float* w1 = (const float*)d_in[2];
  const float* v  = (const float*)d_in[3];
  float* out = (float*)d_out;

  unsigned short* vb = (unsigned short*)d_ws;           // 256 KiB
  float* sh = (float*)(vb + 131072);                    // 8 KiB

  fm_prep<<<72, 256, 0, stream>>>(v, vb, sh);
  fm_main<<<512, 256, 49152, stream>>>(x, w0, w1, vb, sh, out);
}

// Round 17
// 31.577 us; speedup vs baseline: 1.0854x; 1.0854x over previous
//
#include <hip/hip_runtime.h>

#define N_DIM 2048
#define F_DIM 64

typedef __attribute__((ext_vector_type(4))) float  f32x4;
typedef __attribute__((ext_vector_type(8))) short  s16x8;
typedef __attribute__((ext_vector_type(8))) __bf16 bf16x8;

typedef const __attribute__((address_space(1))) void gas_t;
typedef __attribute__((address_space(3))) void las_t;

static __device__ __forceinline__ unsigned short f2bf(float f) {
  unsigned int u = __builtin_bit_cast(unsigned int, f);
  u += 0x7fffu + ((u >> 16) & 1u);      // RNE to bf16
  return (unsigned short)(u >> 16);
}

// Prep (grid 72):
//  blocks 0..63  — MFMA B-fragments of bf16(v): lane l holds
//    B[k = 8*(l/16)+j][col = l%16], stored [kt(64)][tile(4)][lane(64)][j(8)]
//  blocks 64..71 — s_half[k] = 0.5 * sum_f v[k][f]^2
__global__ __launch_bounds__(256) void fm_prep(const float* __restrict__ v,
                                               unsigned short* __restrict__ vb,
                                               float* __restrict__ sh) {
  const int blk = blockIdx.x;
  const int tid = threadIdx.x;
  if (blk < 64) {
    const int g  = blk * 256 + tid;
    const int fl = g & 63;
    const int t  = (g >> 6) & 3;
    const int kt = g >> 8;
    const int kbase = kt * 32 + ((fl >> 4) << 3);
    const int f = t * 16 + (fl & 15);
    s16x8 a;
#pragma unroll
    for (int j = 0; j < 8; ++j)
      a[j] = (short)f2bf(v[(size_t)(kbase + j) * F_DIM + f]);
    *(s16x8*)(vb + (size_t)g * 8) = a;
  } else {
    const int k = (blk - 64) * 256 + tid;
    const f32x4* row = (const f32x4*)(v + (size_t)k * F_DIM);
    float s = 0.0f;
#pragma unroll
    for (int i = 0; i < 16; ++i) {
      f32x4 q = row[i];
      s += q[0]*q[0] + q[1]*q[1] + q[2]*q[2] + q[3]*q[3];
    }
    sh[k] = 0.5f * s;
  }
}

// Main: 512 blocks x 256 threads (4 waves), R7 wave/tile decomposition.
// x staged via global_load_lds (cached — benefits from cross-replay L3
// residency; NT variant measured 7% slower, R16) into WAVE-PRIVATE
// double-buffered 4 KiB slabs. Each 128-B line covered by EXACTLY ONE
// instruction (8 lanes x 16 B, XOR-permuted chunks). No mid-loop barriers:
// counted s_waitcnt vmcnt(N) + sched_barrier fences (N=12 steady, 8@s0,
// 4@s15; FIFO order vb(s+1) -> wait slab s -> compute -> gload s+2).
// vb register-prefetch depth 1 (cached, L2-resident). lin = x.w1 - 0.5*x^2.s
// in fp32 (w1/sh from LDS). Epilogue overlays accW/linL on the slab region.
__global__ __launch_bounds__(256, 2) void fm_main(const float* __restrict__ x,
                                                  const float* __restrict__ w0,
                                                  const float* __restrict__ w1,
                                                  const unsigned short* __restrict__ vb,
                                                  const float* __restrict__ sh,
                                                  float* __restrict__ out) {
  extern __shared__ __align__(16) char smem[];
  // layout: [0,32K) wave slabs (w*8K + buf*4K); [32K,40K) w1L; [40K,48K) shL
  // epilogue overlay: [0,24K) accW, [24K,24.5K) linL
  const int tid  = threadIdx.x;
  const int lane = tid & 63;
  const int w    = tid >> 6;            // 0..3
  const int rowbase = blockIdx.x * 32;
  const int g8   = ((lane >> 4) << 3);  // fragment k-subchunk: 0,8,16,24

  float* w1L = (float*)(smem + 32768);
  float* shL = (float*)(smem + 40960);
  char*  slab0 = smem + (w << 13);      // this wave's buf 0
  char*  slab1 = slab0 + 4096;          // buf 1

  const int kw = w * 512;               // this wave's K range (16 slabs of 32)

  // staging src: lane l covers row (l>>3) of 8-row group, chunk (l&7)^(l>>3)
  // -> LDS linear [row][chunk'] holds x[row][chunk' ^ (row&7)]
  const float* xgl = x + (size_t)(rowbase + (lane >> 3)) * N_DIM + kw
                   + (((lane & 7) ^ (lane >> 3)) << 2);
  const unsigned short* vbase = vb + ((size_t)w * 4096 + lane) * 8;

  // fragment ds offsets: tile h row = 16h+(l&15); chunk c ^ (row&7), row&7=l&7
  const int r7  = lane & 7;
  const int c0  = (lane >> 4) << 1;
  const int offA0 = (lane & 15) * 128 + (((c0)     ^ r7) << 4);
  const int offB0 = (lane & 15) * 128 + (((c0 + 1) ^ r7) << 4);
  const int offA1 = offA0 + 2048;       // rows 16-31
  const int offB1 = offB0 + 2048;

  // ---- stage w1/sh into LDS; barrier drains these 4 loads only ----
  {
    const int t8 = tid << 3;
    *(f32x4*)&w1L[t8]     = *(const f32x4*)(w1 + t8);
    *(f32x4*)&w1L[t8 + 4] = *(const f32x4*)(w1 + t8 + 4);
    *(f32x4*)&shL[t8]     = *(const f32x4*)(sh + t8);
    *(f32x4*)&shL[t8 + 4] = *(const f32x4*)(sh + t8 + 4);
  }
  __syncthreads();

  // ---- prologue (FIFO order matters): vb(0), gload slab0, gload slab1 ----
  s16x8 pb[2][4];
#pragma unroll
  for (int t = 0; t < 4; ++t)
    pb[0][t] = *(const s16x8*)(vbase + t * 512);
#pragma unroll
  for (int i = 0; i < 4; ++i)
    __builtin_amdgcn_global_load_lds((gas_t*)(xgl + (size_t)i * 8 * N_DIM),
                                     (las_t*)(slab0 + i * 1024), 16, 0, 0);
#pragma unroll
  for (int i = 0; i < 4; ++i)
    __builtin_amdgcn_global_load_lds((gas_t*)(xgl + (size_t)i * 8 * N_DIM + 32),
                                     (las_t*)(slab1 + i * 1024), 16, 0, 0);

  f32x4 acc[2][4] = {};
  float linA = 0.0f, linB = 0.0f;

#pragma unroll
  for (int s = 0; s < 16; ++s) {
    // 1. vb prefetch FIRST (depth 1, L2-resident)
    if (s < 15) {
      const unsigned short* vbp = vbase + (size_t)(s + 1) * 2048;
#pragma unroll
      for (int t = 0; t < 4; ++t)
        pb[(s + 1) & 1][t] = *(const s16x8*)(vbp + t * 512);
    }
    // 2. wait for slab s (counted; never drains the pipeline)
    __builtin_amdgcn_sched_barrier(0);
    if (s == 0)       asm volatile("s_waitcnt vmcnt(8)"  ::: "memory");
    else if (s == 15) asm volatile("s_waitcnt vmcnt(4)"  ::: "memory");
    else              asm volatile("s_waitcnt vmcnt(12)" ::: "memory");
    __builtin_amdgcn_sched_barrier(0);
    // 3. fragment reads from slab s
    const char* xq = (s & 1) ? slab1 : slab0;
    f32x4 xa = *(const f32x4*)(xq + offA0);
    f32x4 xb = *(const f32x4*)(xq + offB0);
    f32x4 xc = *(const f32x4*)(xq + offA1);
    f32x4 xd = *(const f32x4*)(xq + offB1);
    const int ki = kw + s * 32 + g8;
    f32x4 wa  = *(const f32x4*)(&w1L[ki]);
    f32x4 wb2 = *(const f32x4*)(&w1L[ki + 4]);
    f32x4 sa  = *(const f32x4*)(&shL[ki]);
    f32x4 sb2 = *(const f32x4*)(&shL[ki + 4]);
    // 4. compute
#pragma unroll
    for (int i = 0; i < 4; ++i) {
      linA = fmaf(xa[i], wa[i]  - xa[i] * sa[i],  linA);
      linA = fmaf(xb[i], wb2[i] - xb[i] * sb2[i], linA);
      linB = fmaf(xc[i], wa[i]  - xc[i] * sa[i],  linB);
      linB = fmaf(xd[i], wb2[i] - xd[i] * sb2[i], linB);
    }
    bf16x8 Alo, Ahi;
#pragma unroll
    for (int i = 0; i < 4; ++i) {
      Alo[i]     = (__bf16)xa[i];
      Alo[4 + i] = (__bf16)xb[i];
      Ahi[i]     = (__bf16)xc[i];
      Ahi[4 + i] = (__bf16)xd[i];
    }
#pragma unroll
    for (int t = 0; t < 4; ++t) {
      bf16x8 Bv = __builtin_bit_cast(bf16x8, pb[s & 1][t]);
      acc[0][t] = __builtin_amdgcn_mfma_f32_16x16x32_bf16(Alo, Bv, acc[0][t], 0, 0, 0);
      acc[1][t] = __builtin_amdgcn_mfma_f32_16x16x32_bf16(Ahi, Bv, acc[1][t], 0, 0, 0);
    }
    // 5. refill this buffer with slab s+2 (reads above already sampled LDS;
    //    the async write lands >=400cyc after issue, far later)
    __builtin_amdgcn_sched_barrier(0);
    if (s < 14) {
      char* dst = (s & 1) ? slab1 : slab0;
#pragma unroll
      for (int i = 0; i < 4; ++i)
        __builtin_amdgcn_global_load_lds(
            (gas_t*)(xgl + (size_t)i * 8 * N_DIM + (s + 2) * 32),
            (las_t*)(dst + i * 1024), 16, 0, 0);
    }
  }

  // ---- lin reduce: lanes {r,r+16,r+32,r+48} hold partials of row r ----
  linA += __shfl_xor(linA, 16);
  linA += __shfl_xor(linA, 32);
  linB += __shfl_xor(linB, 16);
  linB += __shfl_xor(linB, 32);

  // ---- epilogue overlays the slab region: all waves must be done ----
  __syncthreads();
  f32x4 (*accW)[8][64] = (f32x4(*)[8][64])smem;           // [3][8][64]
  float (*linL)[2][16] = (float(*)[2][16])(smem + 24576); // [4][2][16]

  if (lane < 16) {
    linL[w][0][lane] = linA;
    linL[w][1][lane] = linB;
  }
  if (w > 0) {
#pragma unroll
    for (int h = 0; h < 2; ++h)
#pragma unroll
      for (int t = 0; t < 4; ++t)
        accW[w - 1][h * 4 + t][lane] = acc[h][t];
  }
  __syncthreads();

  if (w == 0) {
#pragma unroll
    for (int ww = 0; ww < 3; ++ww)
#pragma unroll
      for (int h = 0; h < 2; ++h)
#pragma unroll
        for (int t = 0; t < 4; ++t)
          acc[h][t] += accW[ww][h * 4 + t][lane];

    // C layout: col = lane&15 (within F-tile t), row = 4*(lane>>4) + r
    float p[2][4];
#pragma unroll
    for (int h = 0; h < 2; ++h)
#pragma unroll
      for (int r = 0; r < 4; ++r) {
        float q = 0.0f;
#pragma unroll
        for (int t = 0; t < 4; ++t)
          q += acc[h][t][r] * acc[h][t][r];
        q += __shfl_xor(q, 1);
        q += __shfl_xor(q, 2);
        q += __shfl_xor(q, 4);
        q += __shfl_xor(q, 8);
        p[h][r] = q;
      }
    if ((lane & 15) == 0) {
      const int g = lane >> 4;
      const float w0v = w0[0];
#pragma unroll
      for (int h = 0; h < 2; ++h)
#pragma unroll
        for (int r = 0; r < 4; ++r) {
          const int row = g * 4 + r;
          float lt = linL[0][h][row] + linL[1][h][row]
                   + linL[2][h][row] + linL[3][h][row];
          out[rowbase + h * 16 + row] = w0v + lt + 0.5f * p[h][r];
        }
    }
  }
}

extern "C" void kernel_launch(void* const* d_in, const int* in_sizes, int n_in,
                              void* d_out, int out_size, void* d_ws, size_t ws_size,
                              hipStream_t stream) {
  const float* x  = (const float*)d_in[0];
  const float* w0 = (const float*)d_in[1];
  const float* w1 = (const float*)d_in[2];
  const float* v  = (const float*)d_in[3];
  float* out = (float*)d_out;

  unsigned short* vb = (unsigned short*)d_ws;           // 256 KiB
  float* sh = (float*)(vb + 131072);                    // 8 KiB

  fm_prep<<<72, 256, 0, stream>>>(v, vb, sh);
  fm_main<<<512, 256, 49152, stream>>>(x, w0, w1, vb, sh, out);
}